// Round 1
// baseline (1280.570 us; speedup 1.0000x reference)
//
#include <hip/hip_runtime.h>
#include <float.h>

#define F_DIM 256
#define N_DIM 512
#define B_DIM 192
#define K_TOP 10

// ---------------------------------------------------------------------------
// k_combine: Wc[f][j] = sum_h g_w[h,f]*w1[h,j]  (fold conv1x1 into layer-1 W)
//            block F_DIM computes bc[j] = sum_h g_b[h]*w1[h,j]
// ---------------------------------------------------------------------------
__global__ __launch_bounds__(256) void k_combine(const float* __restrict__ g_w,
                                                 const float* __restrict__ g_b,
                                                 const float* __restrict__ w1,
                                                 float* __restrict__ Wc,
                                                 float* __restrict__ bc) {
    const int j = threadIdx.x;
    const int f = blockIdx.x;
    if (f < F_DIM) {
        float acc = 0.f;
        for (int h = 0; h < F_DIM; ++h) acc += g_w[h * F_DIM + f] * w1[h * F_DIM + j];
        Wc[f * F_DIM + j] = acc;
    } else {
        float acc = 0.f;
        for (int h = 0; h < F_DIM; ++h) acc += g_b[h] * w1[h * F_DIM + j];
        bc[j] = acc;
    }
}

// ---------------------------------------------------------------------------
// k_topk: per (b, n0..n0+7): A row = v[:,n]^T v[:,m] for all m; top-10 per row
// stores raw top values into wb[row*11+0..9], indices, deg=sum(top)+1.
// Block 256 thr: thread t owns cols 2t,2t+1 x 8 rows. fp32 (selection safety).
// ---------------------------------------------------------------------------
__global__ __launch_bounds__(256) void k_topk(const float* __restrict__ v,
                                              float* __restrict__ deg,
                                              int* __restrict__ idxb,
                                              float* __restrict__ wb) {
    const int b = blockIdx.y;
    const int n0 = blockIdx.x * 8;
    const int t = threadIdx.x;
    const float* vb = v + (size_t)b * F_DIM * N_DIM;
    __shared__ float vn[8][F_DIM];    // vn[r][f] = v[b,f,n0+r]
    __shared__ float at[8][N_DIM];    // A tile rows

    for (int i = t; i < 8 * F_DIM; i += 256) {
        int f = i >> 3, r = i & 7;
        vn[r][f] = vb[f * N_DIM + n0 + r];
    }
    __syncthreads();

    float2 acc[8];
#pragma unroll
    for (int r = 0; r < 8; ++r) acc[r] = make_float2(0.f, 0.f);
    const int m0 = t * 2;
    for (int f4 = 0; f4 < F_DIM; f4 += 4) {
        float2 vm[4];
#pragma unroll
        for (int q = 0; q < 4; ++q)
            vm[q] = *(const float2*)&vb[(size_t)(f4 + q) * N_DIM + m0];
#pragma unroll
        for (int r = 0; r < 8; ++r) {
            float4 a4 = *(const float4*)&vn[r][f4];
            acc[r].x += a4.x * vm[0].x; acc[r].y += a4.x * vm[0].y;
            acc[r].x += a4.y * vm[1].x; acc[r].y += a4.y * vm[1].y;
            acc[r].x += a4.z * vm[2].x; acc[r].y += a4.z * vm[2].y;
            acc[r].x += a4.w * vm[3].x; acc[r].y += a4.w * vm[3].y;
        }
    }
#pragma unroll
    for (int r = 0; r < 8; ++r) *(float2*)&at[r][m0] = acc[r];
    __syncthreads();

    // selection: wave w handles rows 2w, 2w+1; lane owns 8 cols in registers
    const int lane = t & 63;
    const int w = t >> 6;
    for (int rr = 0; rr < 2; ++rr) {
        const int r = w * 2 + rr;
        const int row = b * N_DIM + n0 + r;
        float vreg[8];
        *(float4*)&vreg[0] = *(const float4*)&at[r][lane * 8];
        *(float4*)&vreg[4] = *(const float4*)&at[r][lane * 8 + 4];
        float sum = 0.f;
        for (int it = 0; it < K_TOP; ++it) {
            float bv = -FLT_MAX; int bi = N_DIM;
#pragma unroll
            for (int k = 0; k < 8; ++k) {
                if (vreg[k] > bv) { bv = vreg[k]; bi = lane * 8 + k; }  // lowest idx on tie
            }
#pragma unroll
            for (int off = 32; off; off >>= 1) {
                float ov = __shfl_xor(bv, off, 64);
                int   oi = __shfl_xor(bi, off, 64);
                if (ov > bv || (ov == bv && oi < bi)) { bv = ov; bi = oi; }
            }
            sum += bv;
            if ((bi >> 3) == lane) vreg[bi & 7] = -FLT_MAX;
            if (lane == 0) {
                idxb[row * K_TOP + it] = bi;
                wb[row * (K_TOP + 1) + it] = bv;
            }
        }
        if (lane == 0) deg[row] = sum + 1.0f;   // +1 from added identity
    }
}

// ---------------------------------------------------------------------------
// k_scale: wb[i] <- d_n * a_i * d_m ; wb[10] <- d_n^2 (identity term)
// ---------------------------------------------------------------------------
__global__ __launch_bounds__(256) void k_scale(const float* __restrict__ deg,
                                               const int* __restrict__ idxb,
                                               float* __restrict__ wb) {
    const int row = blockIdx.x * 256 + threadIdx.x;
    const float dg = deg[row];
    const float dn = (dg == 0.f) ? 0.f : 1.f / sqrtf(dg);
    const int bb = (row >> 9) << 9;   // batch base row
#pragma unroll
    for (int i = 0; i < K_TOP; ++i) {
        int m = idxb[row * K_TOP + i];
        float dgm = deg[bb + m];
        float dm = (dgm == 0.f) ? 0.f : 1.f / sqrtf(dgm);
        wb[row * (K_TOP + 1) + i] = dn * wb[row * (K_TOP + 1) + i] * dm;
    }
    wb[row * (K_TOP + 1) + K_TOP] = dn * dn;
}

// ---------------------------------------------------------------------------
// k_gemm: per batch C[M=512, 256] = A[512,256] * Bw[256,256] (+bias)
// TRANS_A: A[n,f] read as v[b, f*N + n] (v^T). 128x128 tile, 8x8 micro, BK=16.
// ---------------------------------------------------------------------------
template <bool TRANS_A, bool ADD_BIAS>
__global__ __launch_bounds__(256) void k_gemm(const float* __restrict__ A,
                                              const float* __restrict__ Bw,
                                              const float* __restrict__ bias,
                                              float* __restrict__ C) {
    __shared__ float As[16][128];
    __shared__ float Bs[16][128];
    const int b = blockIdx.z;
    const int m0 = blockIdx.x * 128;
    const int j0 = blockIdx.y * 128;
    const int t = threadIdx.x;
    const int tx = t & 15, ty = t >> 4;
    const float* Ab = A + (size_t)b * F_DIM * N_DIM;

    float acc[8][8];
#pragma unroll
    for (int i = 0; i < 8; ++i)
#pragma unroll
        for (int j = 0; j < 8; ++j) acc[i][j] = 0.f;

    for (int f0 = 0; f0 < F_DIM; f0 += 16) {
        if (TRANS_A) {
#pragma unroll
            for (int i = 0; i < 8; ++i) {
                int ii = t + i * 256;
                int k = ii >> 7, mm = ii & 127;
                As[k][mm] = Ab[(size_t)(f0 + k) * N_DIM + m0 + mm];
            }
        } else {
#pragma unroll
            for (int i = 0; i < 8; ++i) {
                int ii = t + i * 256;
                int mm = ii >> 4, k = ii & 15;
                As[k][mm] = Ab[(size_t)(m0 + mm) * F_DIM + f0 + k];
            }
        }
#pragma unroll
        for (int i = 0; i < 8; ++i) {
            int ii = t + i * 256;
            int k = ii >> 7, jj = ii & 127;
            Bs[k][jj] = Bw[(size_t)(f0 + k) * F_DIM + j0 + jj];
        }
        __syncthreads();
#pragma unroll
        for (int k = 0; k < 16; ++k) {
            float4 a0 = *(const float4*)&As[k][ty * 8];
            float4 a1 = *(const float4*)&As[k][ty * 8 + 4];
            float4 b0 = *(const float4*)&Bs[k][tx * 8];
            float4 b1 = *(const float4*)&Bs[k][tx * 8 + 4];
            float a[8] = {a0.x, a0.y, a0.z, a0.w, a1.x, a1.y, a1.z, a1.w};
            float bb[8] = {b0.x, b0.y, b0.z, b0.w, b1.x, b1.y, b1.z, b1.w};
#pragma unroll
            for (int i = 0; i < 8; ++i)
#pragma unroll
                for (int j = 0; j < 8; ++j) acc[i][j] += a[i] * bb[j];
        }
        __syncthreads();
    }
#pragma unroll
    for (int i = 0; i < 8; ++i) {
        int m = m0 + ty * 8 + i;
        float* Crow = C + ((size_t)b * N_DIM + m) * F_DIM + j0 + tx * 8;
#pragma unroll
        for (int j = 0; j < 8; ++j) {
            float x = acc[i][j];
            if (ADD_BIAS) x += bias[j0 + tx * 8 + j];
            Crow[j] = x;
        }
    }
}

// ---------------------------------------------------------------------------
// k_spmm: Y[row,:] = (opt relu)( sum_i w_i * X[b, id_i, :] + wself*X[row,:] + bias )
// ---------------------------------------------------------------------------
template <bool RELU>
__global__ __launch_bounds__(256) void k_spmm(const float* __restrict__ X,
                                              const int* __restrict__ idxb,
                                              const float* __restrict__ wb,
                                              const float* __restrict__ bias,
                                              float* __restrict__ Y) {
    const int row = blockIdx.x;
    const int j = threadIdx.x;
    const int b = row >> 9;
    const float* Xb = X + ((size_t)b << 9) * F_DIM;
    const int* id = idxb + row * K_TOP;
    const float* w = wb + row * (K_TOP + 1);
    float acc = w[K_TOP] * X[(size_t)row * F_DIM + j] + bias[j];
#pragma unroll
    for (int i = 0; i < K_TOP; ++i)
        acc += w[i] * Xb[((size_t)id[i] << 8) + j];
    if (RELU) acc = fmaxf(acc, 0.f);
    Y[(size_t)row * F_DIM + j] = acc;
}

// ---------------------------------------------------------------------------
// k_trans_res: out[b,f,n] = X[b,n,f] + v[b,f,n]   (32x32 LDS transpose)
// ---------------------------------------------------------------------------
__global__ __launch_bounds__(256) void k_trans_res(const float* __restrict__ X,
                                                   const float* __restrict__ v,
                                                   float* __restrict__ out) {
    __shared__ float tile[32][33];
    const int b = blockIdx.z;
    const int n0 = blockIdx.x * 32;
    const int f0 = blockIdx.y * 32;
    const int tx = threadIdx.x & 31, ty = threadIdx.x >> 5;
#pragma unroll
    for (int q = 0; q < 4; ++q) {
        int n = n0 + ty + q * 8;
        tile[ty + q * 8][tx] = X[((size_t)b * N_DIM + n) * F_DIM + f0 + tx];
    }
    __syncthreads();
#pragma unroll
    for (int q = 0; q < 4; ++q) {
        size_t o = (size_t)b * F_DIM * N_DIM + (size_t)(f0 + ty + q * 8) * N_DIM + n0 + tx;
        out[o] = tile[tx][ty + q * 8] + v[o];
    }
}

// ---------------------------------------------------------------------------
extern "C" void kernel_launch(void* const* d_in, const int* in_sizes, int n_in,
                              void* d_out, int out_size, void* d_ws, size_t ws_size,
                              hipStream_t stream) {
    const float* v   = (const float*)d_in[0];
    const float* g_w = (const float*)d_in[1];
    const float* g_b = (const float*)d_in[2];
    const float* w1  = (const float*)d_in[3];
    const float* b1  = (const float*)d_in[4];
    const float* w2  = (const float*)d_in[5];
    const float* b2  = (const float*)d_in[6];
    float* out = (float*)d_out;

    const size_t S = (size_t)B_DIM * N_DIM * F_DIM;   // 25,165,824 floats
    float* bufA = (float*)d_ws;                       // h1, then h2
    float* bufB = bufA + S;                           // x1, then x2
    float* Wc   = bufB + S;                           // 65536
    float* bc   = Wc + F_DIM * F_DIM;                 // 256
    float* deg  = bc + F_DIM;                         // B*N
    float* wb   = deg + (size_t)B_DIM * N_DIM;        // B*N*11
    int*   idxb = (int*)(wb + (size_t)B_DIM * N_DIM * (K_TOP + 1));  // B*N*10
    // total ~210 MB of workspace

    // fold conv1x1 weight into layer-1 weight: Wc = g_w^T @ w1, bc = g_b @ w1
    k_combine<<<dim3(F_DIM + 1), 256, 0, stream>>>(g_w, g_b, w1, Wc, bc);
    // affinity + top-K + deg (fp32 for selection fidelity)
    k_topk<<<dim3(N_DIM / 8, B_DIM), 256, 0, stream>>>(v, deg, idxb, wb);
    // h1 = v^T @ Wc + bc   -> bufA
    k_gemm<true, true><<<dim3(4, 2, B_DIM), 256, 0, stream>>>(v, Wc, bc, bufA);
    // normalize kept edge weights
    k_scale<<<dim3(B_DIM * N_DIM / 256), 256, 0, stream>>>(deg, idxb, wb);
    // x1 = relu(A_hat @ h1 + b1)  -> bufB
    k_spmm<true><<<dim3(B_DIM * N_DIM), 256, 0, stream>>>(bufA, idxb, wb, b1, bufB);
    // h2 = x1 @ w2   -> bufA
    k_gemm<false, false><<<dim3(4, 2, B_DIM), 256, 0, stream>>>(bufB, w2, nullptr, bufA);
    // x2 = A_hat @ h2 + b2  -> bufB
    k_spmm<false><<<dim3(B_DIM * N_DIM), 256, 0, stream>>>(bufA, idxb, wb, b2, bufB);
    // out = x2^T + v
    k_trans_res<<<dim3(N_DIM / 32, F_DIM / 32, B_DIM), 256, 0, stream>>>(bufB, v, out);
}

// Round 2
// 1080.858 us; speedup vs baseline: 1.1848x; 1.1848x over previous
//
#include <hip/hip_runtime.h>
#include <float.h>

#define F_DIM 256
#define N_DIM 512
#define B_DIM 192
#define K_TOP 10

typedef __attribute__((ext_vector_type(8))) short short8;
typedef __attribute__((ext_vector_type(4))) float f32x4;

__device__ inline unsigned short f2bf(float x) {
    unsigned u = __builtin_bit_cast(unsigned, x);
    return (unsigned short)((u + 0x7fffu + ((u >> 16) & 1u)) >> 16);
}

// ---------------------------------------------------------------------------
// k_combine: Wc[f][j] = sum_h g_w[h,f]*w1[h,j]; block F_DIM does bc = g_b @ w1
// ---------------------------------------------------------------------------
__global__ __launch_bounds__(256) void k_combine(const float* __restrict__ g_w,
                                                 const float* __restrict__ g_b,
                                                 const float* __restrict__ w1,
                                                 float* __restrict__ Wc,
                                                 float* __restrict__ bc) {
    const int j = threadIdx.x;
    const int f = blockIdx.x;
    if (f < F_DIM) {
        float acc = 0.f;
        for (int h = 0; h < F_DIM; ++h) acc += g_w[h * F_DIM + f] * w1[h * F_DIM + j];
        Wc[f * F_DIM + j] = acc;
    } else {
        float acc = 0.f;
        for (int h = 0; h < F_DIM; ++h) acc += g_b[h] * w1[h * F_DIM + j];
        bc[j] = acc;
    }
}

// ---------------------------------------------------------------------------
// k_to_bf16t: vt[b][n][f] = bf16(v[b][f][n])   (32x32 LDS transpose + convert)
// ---------------------------------------------------------------------------
__global__ __launch_bounds__(256) void k_to_bf16t(const float* __restrict__ v,
                                                  unsigned short* __restrict__ vt) {
    __shared__ float tile[32][33];
    const int b = blockIdx.z;
    const int n0 = blockIdx.x * 32;
    const int f0 = blockIdx.y * 32;
    const int tx = threadIdx.x & 31, ty = threadIdx.x >> 5;
    const float* vb = v + (size_t)b * F_DIM * N_DIM;
#pragma unroll
    for (int q = 0; q < 4; ++q)
        tile[ty + q * 8][tx] = vb[(size_t)(f0 + ty + q * 8) * N_DIM + n0 + tx];
    __syncthreads();
    const int wn = threadIdx.x >> 4;   // 0..15
    const int wf = threadIdx.x & 15;   // 0..15 -> f pair
    unsigned* vt32 = (unsigned*)vt;
#pragma unroll
    for (int q2 = 0; q2 < 2; ++q2) {
        int row = wn + q2 * 16;        // n-local
        unsigned lo = f2bf(tile[wf * 2][row]);
        unsigned hi = f2bf(tile[wf * 2 + 1][row]);
        vt32[(size_t)(b * N_DIM + n0 + row) * (F_DIM / 2) + (f0 >> 1) + wf] = lo | (hi << 16);
    }
}

// ---------------------------------------------------------------------------
// k_topk_mfma: per (b, 16-row tile): A rows = vt[n,:] @ vt[m,:]^T via MFMA,
// then top-10 selection per row. Stage vt[0:512][f0:f0+32] in LDS per k-step
// (global_load_lds, linear dest + inverse-swizzled src; swizzled frag reads).
// ---------------------------------------------------------------------------
__global__ __launch_bounds__(256) void k_topk_mfma(const unsigned short* __restrict__ vt,
                                                   float* __restrict__ deg,
                                                   int* __restrict__ idxb,
                                                   float* __restrict__ wb) {
    __shared__ unsigned short stage[N_DIM * 32];   // 32 KB, swizzled 16B slots
    __shared__ float at[16 * 514];                 // 32.9 KB, padded rows

    const int b = blockIdx.y;
    const int n0loc = blockIdx.x * 16;
    const int t = threadIdx.x;
    const int w = t >> 6;          // wave 0..3
    const int l = t & 63;          // lane
    const int l15 = t & 15;
    const int g = (t >> 4) & 3;    // k-group for fragments
    const unsigned short* vtb = vt + (size_t)b * N_DIM * F_DIM;

    f32x4 acc[8];
#pragma unroll
    for (int mt = 0; mt < 8; ++mt) acc[mt] = (f32x4){0.f, 0.f, 0.f, 0.f};

    for (int f0 = 0; f0 < F_DIM; f0 += 32) {
        // ---- stage vt[0:512][f0:f0+32] -> LDS (wave w covers m in [w*128, w*128+128)) ----
#pragma unroll
        for (int c8 = 0; c8 < 8; ++c8) {
            int m = w * 128 + c8 * 16 + (l >> 2);
            int sg = (l & 3) ^ ((m >> 1) & 3);                 // inverse swizzle on SOURCE
            const unsigned short* src = vtb + (size_t)m * F_DIM + f0 + sg * 8;
            __builtin_amdgcn_global_load_lds(
                (const __attribute__((address_space(1))) void*)src,
                (__attribute__((address_space(3))) void*)((char*)stage + (w * 8 + c8) * 1024),
                16, 0, 0);
        }
        __syncthreads();
        // ---- fragments + MFMA ----
        {
            int ma = n0loc + l15;
            short8 a = *(const short8*)((const char*)stage +
                         ma * 64 + ((g ^ ((ma >> 1) & 3)) << 4));
#pragma unroll
            for (int mt = 0; mt < 8; ++mt) {
                int mb = w * 128 + mt * 16 + l15;
                short8 bf = *(const short8*)((const char*)stage +
                             mb * 64 + ((g ^ ((mb >> 1) & 3)) << 4));
                acc[mt] = __builtin_amdgcn_mfma_f32_16x16x32_bf16(a, bf, acc[mt], 0, 0, 0);
            }
        }
        __syncthreads();
    }

    // ---- scatter accumulators to at[16][514] (2-way max on banks: free) ----
#pragma unroll
    for (int mt = 0; mt < 8; ++mt) {
        int col = w * 128 + mt * 16 + l15;
#pragma unroll
        for (int q = 0; q < 4; ++q)
            at[(g * 4 + q) * 514 + col] = acc[mt][q];
    }
    __syncthreads();

    // ---- top-10 per row; wave w owns rows w*4 .. w*4+3 ----
    for (int rr = 0; rr < 4; ++rr) {
        const int r = w * 4 + rr;
        const int row = b * N_DIM + n0loc + r;
        float vreg[8];
#pragma unroll
        for (int k = 0; k < 8; ++k) vreg[k] = at[r * 514 + l + 64 * k];  // conflict-free
        float sum = 0.f;
        for (int it = 0; it < K_TOP; ++it) {
            float bv = -FLT_MAX; int bi = 0x7fffffff;
#pragma unroll
            for (int k = 0; k < 8; ++k) {
                if (vreg[k] > bv) { bv = vreg[k]; bi = l + 64 * k; }   // ascending col scan
            }
#pragma unroll
            for (int off = 32; off; off >>= 1) {
                float ov = __shfl_xor(bv, off, 64);
                int   oi = __shfl_xor(bi, off, 64);
                if (ov > bv || (ov == bv && oi < bi)) { bv = ov; bi = oi; }
            }
            sum += bv;
#pragma unroll
            for (int k = 0; k < 8; ++k)                                 // static-index knockout
                if ((bi >> 6) == k && (bi & 63) == l) vreg[k] = -FLT_MAX;
            if (l == 0) {
                idxb[row * K_TOP + it] = bi;
                wb[row * (K_TOP + 1) + it] = bv;
            }
        }
        if (l == 0) deg[row] = sum + 1.0f;
    }
}

// ---------------------------------------------------------------------------
// k_scale: wb[i] <- d_n * a_i * d_m ; wb[10] <- d_n^2 (identity term)
// ---------------------------------------------------------------------------
__global__ __launch_bounds__(256) void k_scale(const float* __restrict__ deg,
                                               const int* __restrict__ idxb,
                                               float* __restrict__ wb) {
    const int row = blockIdx.x * 256 + threadIdx.x;
    const float dg = deg[row];
    const float dn = (dg == 0.f) ? 0.f : 1.f / sqrtf(dg);
    const int bb = (row >> 9) << 9;
#pragma unroll
    for (int i = 0; i < K_TOP; ++i) {
        int m = idxb[row * K_TOP + i];
        float dgm = deg[bb + m];
        float dm = (dgm == 0.f) ? 0.f : 1.f / sqrtf(dgm);
        wb[row * (K_TOP + 1) + i] = dn * wb[row * (K_TOP + 1) + i] * dm;
    }
    wb[row * (K_TOP + 1) + K_TOP] = dn * dn;
}

// ---------------------------------------------------------------------------
// k_gemm: per batch C[512,256] = A[512,256] * Bw[256,256] (+bias), fp32
// ---------------------------------------------------------------------------
template <bool TRANS_A, bool ADD_BIAS>
__global__ __launch_bounds__(256) void k_gemm(const float* __restrict__ A,
                                              const float* __restrict__ Bw,
                                              const float* __restrict__ bias,
                                              float* __restrict__ C) {
    __shared__ float As[16][128];
    __shared__ float Bs[16][128];
    const int b = blockIdx.z;
    const int m0 = blockIdx.x * 128;
    const int j0 = blockIdx.y * 128;
    const int t = threadIdx.x;
    const int tx = t & 15, ty = t >> 4;
    const float* Ab = A + (size_t)b * F_DIM * N_DIM;

    float acc[8][8];
#pragma unroll
    for (int i = 0; i < 8; ++i)
#pragma unroll
        for (int j = 0; j < 8; ++j) acc[i][j] = 0.f;

    for (int f0 = 0; f0 < F_DIM; f0 += 16) {
        if (TRANS_A) {
#pragma unroll
            for (int i = 0; i < 8; ++i) {
                int ii = t + i * 256;
                int k = ii >> 7, mm = ii & 127;
                As[k][mm] = Ab[(size_t)(f0 + k) * N_DIM + m0 + mm];
            }
        } else {
#pragma unroll
            for (int i = 0; i < 8; ++i) {
                int ii = t + i * 256;
                int mm = ii >> 4, k = ii & 15;
                As[k][mm] = Ab[(size_t)(m0 + mm) * F_DIM + f0 + k];
            }
        }
#pragma unroll
        for (int i = 0; i < 8; ++i) {
            int ii = t + i * 256;
            int k = ii >> 7, jj = ii & 127;
            Bs[k][jj] = Bw[(size_t)(f0 + k) * F_DIM + j0 + jj];
        }
        __syncthreads();
#pragma unroll
        for (int k = 0; k < 16; ++k) {
            float4 a0 = *(const float4*)&As[k][ty * 8];
            float4 a1 = *(const float4*)&As[k][ty * 8 + 4];
            float4 b0 = *(const float4*)&Bs[k][tx * 8];
            float4 b1 = *(const float4*)&Bs[k][tx * 8 + 4];
            float a[8] = {a0.x, a0.y, a0.z, a0.w, a1.x, a1.y, a1.z, a1.w};
            float bb[8] = {b0.x, b0.y, b0.z, b0.w, b1.x, b1.y, b1.z, b1.w};
#pragma unroll
            for (int i = 0; i < 8; ++i)
#pragma unroll
                for (int j = 0; j < 8; ++j) acc[i][j] += a[i] * bb[j];
        }
        __syncthreads();
    }
#pragma unroll
    for (int i = 0; i < 8; ++i) {
        int m = m0 + ty * 8 + i;
        float* Crow = C + ((size_t)b * N_DIM + m) * F_DIM + j0 + tx * 8;
#pragma unroll
        for (int j = 0; j < 8; ++j) {
            float x = acc[i][j];
            if (ADD_BIAS) x += bias[j0 + tx * 8 + j];
            Crow[j] = x;
        }
    }
}

// ---------------------------------------------------------------------------
// k_spmm: Y[row,:] = (opt relu)( sum_i w_i*X[b,id_i,:] + wself*X[row,:] + bias )
// ---------------------------------------------------------------------------
template <bool RELU>
__global__ __launch_bounds__(256) void k_spmm(const float* __restrict__ X,
                                              const int* __restrict__ idxb,
                                              const float* __restrict__ wb,
                                              const float* __restrict__ bias,
                                              float* __restrict__ Y) {
    const int row = blockIdx.x;
    const int j = threadIdx.x;
    const int b = row >> 9;
    const float* Xb = X + ((size_t)b << 9) * F_DIM;
    const int* id = idxb + row * K_TOP;
    const float* w = wb + row * (K_TOP + 1);
    float acc = w[K_TOP] * X[(size_t)row * F_DIM + j] + bias[j];
#pragma unroll
    for (int i = 0; i < K_TOP; ++i)
        acc += w[i] * Xb[((size_t)id[i] << 8) + j];
    if (RELU) acc = fmaxf(acc, 0.f);
    Y[(size_t)row * F_DIM + j] = acc;
}

// ---------------------------------------------------------------------------
// k_trans_res: out[b,f,n] = X[b,n,f] + v[b,f,n]
// ---------------------------------------------------------------------------
__global__ __launch_bounds__(256) void k_trans_res(const float* __restrict__ X,
                                                   const float* __restrict__ v,
                                                   float* __restrict__ out) {
    __shared__ float tile[32][33];
    const int b = blockIdx.z;
    const int n0 = blockIdx.x * 32;
    const int f0 = blockIdx.y * 32;
    const int tx = threadIdx.x & 31, ty = threadIdx.x >> 5;
#pragma unroll
    for (int q = 0; q < 4; ++q) {
        int n = n0 + ty + q * 8;
        tile[ty + q * 8][tx] = X[((size_t)b * N_DIM + n) * F_DIM + f0 + tx];
    }
    __syncthreads();
#pragma unroll
    for (int q = 0; q < 4; ++q) {
        size_t o = (size_t)b * F_DIM * N_DIM + (size_t)(f0 + ty + q * 8) * N_DIM + n0 + tx;
        out[o] = tile[tx][ty + q * 8] + v[o];
    }
}

// ---------------------------------------------------------------------------
extern "C" void kernel_launch(void* const* d_in, const int* in_sizes, int n_in,
                              void* d_out, int out_size, void* d_ws, size_t ws_size,
                              hipStream_t stream) {
    const float* v   = (const float*)d_in[0];
    const float* g_w = (const float*)d_in[1];
    const float* g_b = (const float*)d_in[2];
    const float* w1  = (const float*)d_in[3];
    const float* b1  = (const float*)d_in[4];
    const float* w2  = (const float*)d_in[5];
    const float* b2  = (const float*)d_in[6];
    float* out = (float*)d_out;

    const size_t S = (size_t)B_DIM * N_DIM * F_DIM;
    float* bufA = (float*)d_ws;
    float* bufB = bufA + S;
    float* Wc   = bufB + S;
    float* bc   = Wc + F_DIM * F_DIM;
    float* deg  = bc + F_DIM;
    float* wb   = deg + (size_t)B_DIM * N_DIM;
    int*   idxb = (int*)(wb + (size_t)B_DIM * N_DIM * (K_TOP + 1));
    // vt (bf16, 50.3 MB) aliases bufB (100.7 MB) — dead before spmm1 writes bufB
    unsigned short* vt = (unsigned short*)bufB;

    k_combine<<<dim3(F_DIM + 1), 256, 0, stream>>>(g_w, g_b, w1, Wc, bc);
    k_to_bf16t<<<dim3(N_DIM / 32, F_DIM / 32, B_DIM), 256, 0, stream>>>(v, vt);
    k_topk_mfma<<<dim3(N_DIM / 16, B_DIM), 256, 0, stream>>>(vt, deg, idxb, wb);
    // h1 = v^T @ Wc + bc   -> bufA
    k_gemm<true, true><<<dim3(4, 2, B_DIM), 256, 0, stream>>>(v, Wc, bc, bufA);
    k_scale<<<dim3(B_DIM * N_DIM / 256), 256, 0, stream>>>(deg, idxb, wb);
    // x1 = relu(A_hat @ h1 + b1)  -> bufB (vt now dead)
    k_spmm<true><<<dim3(B_DIM * N_DIM), 256, 0, stream>>>(bufA, idxb, wb, b1, bufB);
    // h2 = x1 @ w2 -> bufA
    k_gemm<false, false><<<dim3(4, 2, B_DIM), 256, 0, stream>>>(bufB, w2, nullptr, bufA);
    // x2 = A_hat @ h2 + b2 -> bufB
    k_spmm<false><<<dim3(B_DIM * N_DIM), 256, 0, stream>>>(bufA, idxb, wb, b2, bufB);
    // out = x2^T + v
    k_trans_res<<<dim3(N_DIM / 32, F_DIM / 32, B_DIM), 256, 0, stream>>>(bufB, v, out);
}

// Round 3
// 662.433 us; speedup vs baseline: 1.9331x; 1.6316x over previous
//
#include <hip/hip_runtime.h>
#include <float.h>

#define F_DIM 256
#define N_DIM 512
#define B_DIM 192
#define K_TOP 10

typedef __attribute__((ext_vector_type(8))) short short8;
typedef __attribute__((ext_vector_type(4))) float f32x4;

__device__ inline unsigned short f2bf(float x) {
    unsigned u = __builtin_bit_cast(unsigned, x);
    return (unsigned short)((u + 0x7fffu + ((u >> 16) & 1u)) >> 16);
}

// ---------------------------------------------------------------------------
// k_combine (grid 514):
//   bx<256 : Wt1[j][f=bx] = bf16( sum_h g_w[h,f]*w1[h,j] )   (folded conv W, B-layout)
//   bx==256: bc[j] = sum_h g_b[h]*w1[h,j]
//   bx>256 : W2t[j][f] = bf16(w2[f][j])
// ---------------------------------------------------------------------------
__global__ __launch_bounds__(256) void k_combine(const float* __restrict__ g_w,
                                                 const float* __restrict__ g_b,
                                                 const float* __restrict__ w1,
                                                 const float* __restrict__ w2,
                                                 unsigned short* __restrict__ Wt1,
                                                 float* __restrict__ bc,
                                                 unsigned short* __restrict__ W2t) {
    const int j = threadIdx.x;
    const int bx = blockIdx.x;
    if (bx < F_DIM) {
        float acc = 0.f;
        for (int h = 0; h < F_DIM; ++h) acc += g_w[h * F_DIM + bx] * w1[h * F_DIM + j];
        Wt1[j * F_DIM + bx] = f2bf(acc);
    } else if (bx == F_DIM) {
        float acc = 0.f;
        for (int h = 0; h < F_DIM; ++h) acc += g_b[h] * w1[h * F_DIM + j];
        bc[j] = acc;
    } else {
        int f = bx - F_DIM - 1;
        W2t[j * F_DIM + f] = f2bf(w2[f * F_DIM + j]);
    }
}

// ---------------------------------------------------------------------------
// k_to_bf16t: vt[b][n][f] = bf16(v[b][f][n])   (32x32 LDS transpose + convert)
// ---------------------------------------------------------------------------
__global__ __launch_bounds__(256) void k_to_bf16t(const float* __restrict__ v,
                                                  unsigned short* __restrict__ vt) {
    __shared__ float tile[32][33];
    const int b = blockIdx.z;
    const int n0 = blockIdx.x * 32;
    const int f0 = blockIdx.y * 32;
    const int tx = threadIdx.x & 31, ty = threadIdx.x >> 5;
    const float* vb = v + (size_t)b * F_DIM * N_DIM;
#pragma unroll
    for (int q = 0; q < 4; ++q)
        tile[ty + q * 8][tx] = vb[(size_t)(f0 + ty + q * 8) * N_DIM + n0 + tx];
    __syncthreads();
    const int wn = threadIdx.x >> 4;
    const int wf = threadIdx.x & 15;
    unsigned* vt32 = (unsigned*)vt;
#pragma unroll
    for (int q2 = 0; q2 < 2; ++q2) {
        int row = wn + q2 * 16;
        unsigned lo = f2bf(tile[wf * 2][row]);
        unsigned hi = f2bf(tile[wf * 2 + 1][row]);
        vt32[(size_t)(b * N_DIM + n0 + row) * (F_DIM / 2) + (f0 >> 1) + wf] = lo | (hi << 16);
    }
}

// ---------------------------------------------------------------------------
// k_topk_reg: block = 64 rows (4 waves x 16), all 512 cols. No LDS, no barriers.
// A-frags hoisted to regs; B-frags register-direct from global (L1/L2-hot).
// Top-10 selection in-register from C-fragments, 4 rows in parallel per wave.
// ---------------------------------------------------------------------------
__global__ __launch_bounds__(256, 2) void k_topk_reg(const unsigned short* __restrict__ vt,
                                                     float* __restrict__ deg,
                                                     int* __restrict__ idxb,
                                                     float* __restrict__ wb) {
    const int b = blockIdx.y;
    const int w = threadIdx.x >> 6;
    const int l = threadIdx.x & 63;
    const int l15 = l & 15;
    const int g = l >> 4;
    const int n0w = blockIdx.x * 64 + w * 16;
    const unsigned short* vtb = vt + (size_t)b * N_DIM * F_DIM;

    // A fragments for all 8 k-steps (rows n0w..n0w+15): 32 VGPRs
    short8 af[8];
#pragma unroll
    for (int s = 0; s < 8; ++s)
        af[s] = *(const short8*)(vtb + (size_t)(n0w + l15) * F_DIM + s * 32 + g * 8);

    f32x4 acc[32];
#pragma unroll
    for (int mt = 0; mt < 32; ++mt) acc[mt] = (f32x4){0.f, 0.f, 0.f, 0.f};

    // mt-outer: B-frag loads for mt+1 pipeline under mt's MFMA chain
#pragma unroll
    for (int mt = 0; mt < 32; ++mt) {
        const unsigned short* bp = vtb + (size_t)(mt * 16 + l15) * F_DIM + g * 8;
#pragma unroll
        for (int s = 0; s < 8; ++s) {
            short8 bf = *(const short8*)(bp + s * 32);
            acc[mt] = __builtin_amdgcn_mfma_f32_16x16x32_bf16(af[s], bf, acc[mt], 0, 0, 0);
        }
    }

    // ---- in-register top-10: 4 q-phases, each handles 4 rows in parallel ----
#pragma unroll
    for (int q = 0; q < 4; ++q) {
        float wv[32];
#pragma unroll
        for (int mt = 0; mt < 32; ++mt) wv[mt] = acc[mt][q];
        const int row = b * N_DIM + n0w + g * 4 + q;   // this lane-group's row
        float sum = 0.f;
        for (int it = 0; it < K_TOP; ++it) {
            float bv = wv[0]; int bi = l15;
#pragma unroll
            for (int mt = 1; mt < 32; ++mt) {
                int ci = mt * 16 + l15;
                if (wv[mt] > bv) { bv = wv[mt]; bi = ci; }
            }
            // reduce within the 16-lane group (offsets 1,2,4,8 stay in-group)
#pragma unroll
            for (int off = 1; off <= 8; off <<= 1) {
                float ov = __shfl_xor(bv, off, 64);
                int   oi = __shfl_xor(bi, off, 64);
                if (ov > bv || (ov == bv && oi < bi)) { bv = ov; bi = oi; }
            }
            sum += bv;
            if ((bi & 15) == l15) {                    // owning lane knocks out
                int kmt = bi >> 4;
#pragma unroll
                for (int mt = 0; mt < 32; ++mt)
                    if (mt == kmt) wv[mt] = -FLT_MAX;
            }
            if (l15 == 0) {
                idxb[row * K_TOP + it] = bi;
                wb[row * (K_TOP + 1) + it] = bv;
            }
        }
        if (l15 == 0) deg[row] = sum + 1.0f;
    }
}

// ---------------------------------------------------------------------------
// k_scale: wb[i] <- d_n * a_i * d_m ; wb[10] <- d_n^2 (identity term)
// ---------------------------------------------------------------------------
__global__ __launch_bounds__(256) void k_scale(const float* __restrict__ deg,
                                               const int* __restrict__ idxb,
                                               float* __restrict__ wb) {
    const int row = blockIdx.x * 256 + threadIdx.x;
    const float dg = deg[row];
    const float dn = (dg == 0.f) ? 0.f : 1.f / sqrtf(dg);
    const int bb = (row >> 9) << 9;
#pragma unroll
    for (int i = 0; i < K_TOP; ++i) {
        int m = idxb[row * K_TOP + i];
        float dgm = deg[bb + m];
        float dm = (dgm == 0.f) ? 0.f : 1.f / sqrtf(dgm);
        wb[row * (K_TOP + 1) + i] = dn * wb[row * (K_TOP + 1) + i] * dm;
    }
    wb[row * (K_TOP + 1) + K_TOP] = dn * dn;
}

// ---------------------------------------------------------------------------
// k_gemm_mfma: per batch C[512,256] = At[512,256](bf16) @ Wt[256,256]^T(bf16)
// Wt stored [j][f] (B-operand layout). Register-direct, no LDS/barriers.
// Block: 128 rows x 256 cols, 4 waves (each 32 rows x 256 cols).
// ---------------------------------------------------------------------------
template <bool ADD_BIAS>
__global__ __launch_bounds__(256, 2) void k_gemm_mfma(const unsigned short* __restrict__ At,
                                                      const unsigned short* __restrict__ Wt,
                                                      const float* __restrict__ bias,
                                                      float* __restrict__ C) {
    const int b = blockIdx.y;
    const int w = threadIdx.x >> 6;
    const int l = threadIdx.x & 63;
    const int l15 = l & 15;
    const int g = l >> 4;
    const int n0w = blockIdx.x * 128 + w * 32;
    const unsigned short* Ab = At + (size_t)b * N_DIM * F_DIM;

    f32x4 acc0[16], acc1[16];
#pragma unroll
    for (int jt = 0; jt < 16; ++jt) {
        acc0[jt] = (f32x4){0.f, 0.f, 0.f, 0.f};
        acc1[jt] = (f32x4){0.f, 0.f, 0.f, 0.f};
    }

    for (int s = 0; s < 8; ++s) {   // runtime loop; acc indices static
        short8 a0 = *(const short8*)(Ab + (size_t)(n0w + l15) * F_DIM + s * 32 + g * 8);
        short8 a1 = *(const short8*)(Ab + (size_t)(n0w + 16 + l15) * F_DIM + s * 32 + g * 8);
#pragma unroll
        for (int jt = 0; jt < 16; ++jt) {
            short8 bf = *(const short8*)(Wt + (size_t)(jt * 16 + l15) * F_DIM + s * 32 + g * 8);
            acc0[jt] = __builtin_amdgcn_mfma_f32_16x16x32_bf16(a0, bf, acc0[jt], 0, 0, 0);
            acc1[jt] = __builtin_amdgcn_mfma_f32_16x16x32_bf16(a1, bf, acc1[jt], 0, 0, 0);
        }
    }

#pragma unroll
    for (int jt = 0; jt < 16; ++jt) {
        float bv = ADD_BIAS ? bias[jt * 16 + l15] : 0.f;
#pragma unroll
        for (int q = 0; q < 4; ++q) {
            int r0 = n0w + g * 4 + q;
            C[((size_t)b * N_DIM + r0) * F_DIM + jt * 16 + l15] = acc0[jt][q] + bv;
            int r1 = n0w + 16 + g * 4 + q;
            C[((size_t)b * N_DIM + r1) * F_DIM + jt * 16 + l15] = acc1[jt][q] + bv;
        }
    }
}

// ---------------------------------------------------------------------------
// k_spmm: per row: Y = (relu?)( sum_i w_i*X[b,id_i,:] + wself*X[row,:] + bias )
// 4 rows per block (one per wave); lane owns float4 (4 cols).
// BF16OUT packs to bf16 (feeds next MFMA GEMM).
// ---------------------------------------------------------------------------
template <bool RELU, bool BF16OUT>
__global__ __launch_bounds__(256) void k_spmm(const float* __restrict__ X,
                                              const int* __restrict__ idxb,
                                              const float* __restrict__ wb,
                                              const float* __restrict__ bias,
                                              void* __restrict__ Y) {
    const int w = threadIdx.x >> 6;
    const int l = threadIdx.x & 63;
    const int row = blockIdx.x * 4 + w;
    const int b = row >> 9;
    const float* Xb = X + ((size_t)b << 9) * F_DIM;
    const int* id = idxb + row * K_TOP;
    const float* wv = wb + row * (K_TOP + 1);

    float4 bv = ((const float4*)bias)[l];
    float4 xv = ((const float4*)(X + (size_t)row * F_DIM))[l];
    float ws = wv[K_TOP];
    float4 acc;
    acc.x = ws * xv.x + bv.x; acc.y = ws * xv.y + bv.y;
    acc.z = ws * xv.z + bv.z; acc.w = ws * xv.w + bv.w;
#pragma unroll
    for (int i = 0; i < K_TOP; ++i) {
        float wi = wv[i];
        float4 gv = ((const float4*)(Xb + ((size_t)id[i] << 8)))[l];
        acc.x += wi * gv.x; acc.y += wi * gv.y;
        acc.z += wi * gv.z; acc.w += wi * gv.w;
    }
    if (RELU) {
        acc.x = fmaxf(acc.x, 0.f); acc.y = fmaxf(acc.y, 0.f);
        acc.z = fmaxf(acc.z, 0.f); acc.w = fmaxf(acc.w, 0.f);
    }
    if (BF16OUT) {
        uint2 p;
        p.x = (unsigned)f2bf(acc.x) | ((unsigned)f2bf(acc.y) << 16);
        p.y = (unsigned)f2bf(acc.z) | ((unsigned)f2bf(acc.w) << 16);
        ((uint2*)Y)[(size_t)row * (F_DIM / 4) + l] = p;
    } else {
        ((float4*)Y)[(size_t)row * (F_DIM / 4) + l] = acc;
    }
}

// ---------------------------------------------------------------------------
// k_trans_res: out[b,f,n] = X[b,n,f] + v[b,f,n]
// ---------------------------------------------------------------------------
__global__ __launch_bounds__(256) void k_trans_res(const float* __restrict__ X,
                                                   const float* __restrict__ v,
                                                   float* __restrict__ out) {
    __shared__ float tile[32][33];
    const int b = blockIdx.z;
    const int n0 = blockIdx.x * 32;
    const int f0 = blockIdx.y * 32;
    const int tx = threadIdx.x & 31, ty = threadIdx.x >> 5;
#pragma unroll
    for (int q = 0; q < 4; ++q) {
        int n = n0 + ty + q * 8;
        tile[ty + q * 8][tx] = X[((size_t)b * N_DIM + n) * F_DIM + f0 + tx];
    }
    __syncthreads();
#pragma unroll
    for (int q = 0; q < 4; ++q) {
        size_t o = (size_t)b * F_DIM * N_DIM + (size_t)(f0 + ty + q * 8) * N_DIM + n0 + tx;
        out[o] = tile[tx][ty + q * 8] + v[o];
    }
}

// ---------------------------------------------------------------------------
extern "C" void kernel_launch(void* const* d_in, const int* in_sizes, int n_in,
                              void* d_out, int out_size, void* d_ws, size_t ws_size,
                              hipStream_t stream) {
    const float* v   = (const float*)d_in[0];
    const float* g_w = (const float*)d_in[1];
    const float* g_b = (const float*)d_in[2];
    const float* w1  = (const float*)d_in[3];
    const float* b1  = (const float*)d_in[4];
    const float* w2  = (const float*)d_in[5];
    const float* b2  = (const float*)d_in[6];
    float* out = (float*)d_out;

    const size_t S = (size_t)B_DIM * N_DIM * F_DIM;
    float* bufA = (float*)d_ws;                     // h1, then h2 (fp32)
    float* bufB = bufA + S;                         // vt(bf16) -> x1bf(bf16) -> x2(fp32)
    float* bc   = bufB + S;
    float* deg  = bc + F_DIM;
    float* wb   = deg + (size_t)B_DIM * N_DIM;
    int*   idxb = (int*)(wb + (size_t)B_DIM * N_DIM * (K_TOP + 1));
    unsigned short* Wt1 = (unsigned short*)(idxb + (size_t)B_DIM * N_DIM * K_TOP);
    unsigned short* W2t = Wt1 + F_DIM * F_DIM;

    unsigned short* vt   = (unsigned short*)bufB;
    unsigned short* x1bf = (unsigned short*)bufB;   // overwrites vt (dead after gemm1)
    float* x2 = bufB;                               // overwrites x1bf (dead after gemm2)

    // weights prep: Wt1 = bf16((g_w^T w1)^T), bc = g_b @ w1, W2t = bf16(w2^T)
    k_combine<<<dim3(2 * F_DIM + 2), 256, 0, stream>>>(g_w, g_b, w1, w2, Wt1, bc, W2t);
    // vt = bf16(v^T)
    k_to_bf16t<<<dim3(N_DIM / 32, F_DIM / 32, B_DIM), 256, 0, stream>>>(v, vt);
    // affinity + top-10 + deg (bf16 MFMA, register-direct)
    k_topk_reg<<<dim3(N_DIM / 64, B_DIM), 256, 0, stream>>>(vt, deg, idxb, wb);
    // h1 = vt @ Wt1^T + bc -> bufA
    k_gemm_mfma<true><<<dim3(N_DIM / 128, B_DIM), 256, 0, stream>>>(vt, Wt1, bc, bufA);
    // normalize kept edge weights
    k_scale<<<dim3(B_DIM * N_DIM / 256), 256, 0, stream>>>(deg, idxb, wb);
    // x1 = relu(A_hat @ h1 + b1) -> x1bf (bf16)
    k_spmm<true, true><<<dim3(B_DIM * N_DIM / 4), 256, 0, stream>>>(bufA, idxb, wb, b1, x1bf);
    // h2 = x1bf @ W2t^T -> bufA
    k_gemm_mfma<false><<<dim3(N_DIM / 128, B_DIM), 256, 0, stream>>>(x1bf, W2t, nullptr, bufA);
    // x2 = A_hat @ h2 + b2 -> bufB (fp32)
    k_spmm<false, false><<<dim3(B_DIM * N_DIM / 4), 256, 0, stream>>>(bufA, idxb, wb, b2, x2);
    // out = x2^T + v
    k_trans_res<<<dim3(N_DIM / 32, F_DIM / 32, B_DIM), 256, 0, stream>>>(x2, v, out);
}